// Round 7
// baseline (2244.364 us; speedup 1.0000x reference)
//
#include <hip/hip_runtime.h>
#include <hip/hip_bf16.h>
#include <stdint.h>

typedef unsigned short u16;
typedef unsigned char u8;
typedef float f32x4 __attribute__((ext_vector_type(4)));
typedef float f32x2 __attribute__((ext_vector_type(2)));
typedef _Float16 f16x2 __attribute__((ext_vector_type(2)));
typedef _Float16 f16x8 __attribute__((ext_vector_type(8)));

#define H      300
#define KP     320          // K padded (320 fp8 bytes per row)
#define BATCH  256
#define NX     128
#define NY     128
#define VY     32000
#define NPAD   32768        // vocab padded
#define MROWS  32512        // 127*256 decoder rows

// Swizzled OW layout (OWS): vocab col v, k -> tile = v>>6 (64 cols x 320 K =
// 20480 B each); within tile: byte = (k>>5)*2048 + ((v>>4)&3)*512 + (v&15)*8
// + ((k>>3)&3)*128 + (k&7).  A wave's MFMA B-fragment (16-col block tc,
// k-slice ks) is the contiguous 512B range [tile*20480 + ks*2048 + tc*512
// + lane*8] -- fully coalesced b64 loads straight to VGPRs.

// workspace layout (bytes)
#define OWS_OFF   0UL
#define OWS_BYTES ((unsigned long)NPAD * KP)           // 10,485,760
#define OWS_PAD   131072UL                             // prefetch overrun pad
#define A8_OFF    (OWS_OFF + OWS_BYTES + OWS_PAD)
#define A8_BYTES  ((unsigned long)MROWS * KP)          // 10,403,840
#define WTE_OFF   (A8_OFF + A8_BYTES)
#define WT_BYTES  (320UL * KP * 4)                     // 320 rows (zero-pad k>=300)
#define WTD_OFF   (WTE_OFF + WT_BYTES)
#define OBP_OFF   (WTD_OFF + WT_BYTES)
#define OBP_BYTES ((unsigned long)NPAD * 4)            // outb with -1e30 pad
#define SE_OFF    (OBP_OFF + OBP_BYTES)
#define SE_BYTES  ((unsigned long)MROWS * 4)

// ---------------- K0: prep (fp8 outW -> swizzled OWS; padded outb; W^T) ----
__global__ __launch_bounds__(256) void k0_prep(const float* __restrict__ outW,
                                               const float* __restrict__ encW,
                                               const float* __restrict__ decW,
                                               const float* __restrict__ outb,
                                               u8* __restrict__ ows,
                                               float* __restrict__ obp,
                                               float* __restrict__ wte,
                                               float* __restrict__ wtd) {
    long id = (long)blockIdx.x * 256 + threadIdx.x;
    const long n1 = (long)NPAD * KP / 4;         // u32 chunks
    if (id < n1) {
        int v = (int)(id / 80), k4 = (int)(id % 80) * 4;
        float4 f = {0.f, 0.f, 0.f, 0.f};
        if (v < VY && k4 < H) f = *(const float4*)&outW[(long)v * H + k4]; // k4<=296 -> full
        int w = __builtin_amdgcn_cvt_pk_fp8_f32(f.x, f.y, 0, false);
        w = __builtin_amdgcn_cvt_pk_fp8_f32(f.z, f.w, w, true);
        long dst = (long)(v >> 6) * 20480 + (k4 >> 5) * 2048 + ((v >> 4) & 3) * 512
                 + (v & 15) * 8 + ((k4 >> 3) & 3) * 128 + (k4 & 7);
        *(unsigned int*)(ows + dst) = (unsigned int)w;
        return;
    }
    long id2 = id - n1;
    if (id2 < NPAD) {                            // padded bias: pad -> -1e30
        obp[id2] = (id2 < VY) ? outb[id2] : -1e30f;
        return;
    }
    id2 -= NPAD;
    if (id2 < 320L * KP) {                       // Wt_enc[k][j] = encW[j][k], 320 rows
        int k = (int)(id2 / KP), j = (int)(id2 % KP);
        wte[id2] = (k < H && j < H) ? encW[j * H + k] : 0.f;
        return;
    }
    id2 -= 320L * KP;
    if (id2 < 320L * KP) {                       // Wt_dec
        int k = (int)(id2 / KP), j = (int)(id2 % KP);
        wtd[id2] = (k < H && j < H) ? decW[j * H + k] : 0.f;
    }
}

// ---------------- K1: register-resident weights, 1 batch elem / block ----
// 256 blocks x 640 threads (10 waves). Thread (s=tid/160, j=tid%160) holds
// W[:, {j, j+160}] for k in [80s, 80s+80) as 80 packed f16 pairs; each b128
// h-broadcast read now feeds 8 fdot2 (2 cols x 4 pairs) -> LDS instrs/step
// roughly halved vs the 1-col layout.
__global__ __launch_bounds__(640) void k1_rnn(const int* __restrict__ x,
                                              const int* __restrict__ y,
                                              const float* __restrict__ enc_emb,
                                              const float* __restrict__ dec_emb,
                                              const float* __restrict__ encb,
                                              const float* __restrict__ decb,
                                              const float* __restrict__ wte,
                                              const float* __restrict__ wtd,
                                              u8* __restrict__ A8) {
    const int tid = threadIdx.x;
    const int s = tid / 160;           // k-slice 0..3
    const int j = tid - s * 160;       // column pair base: cols j, j+160
    const int b = blockIdx.x;

    __shared__ __align__(16) _Float16 hh[320];   // h (fp16), pad >=300 = 0
    __shared__ float part[1280];                 // [slice][col]
    __shared__ __align__(4) u8 a8row[320];

    for (int i = tid; i < 320; i += 640) hh[i] = (_Float16)0.f;

    const bool comb = (tid < 320);     // combine-phase threads, col jc
    const int jc = tid;
    const float be = (comb && jc < H) ? encb[jc] : 0.f;
    const float bd = (comb && jc < H) ? decb[jc] : 0.f;

    // ---- preload encoder weights (2 cols x 40 pairs) ----
    f16x2 wa[40], wc[40];
#pragma unroll
    for (int kk = 0; kk < 40; ++kk) {
        int k0 = s * 80 + 2 * kk;
        wa[kk] = (f16x2){(_Float16)wte[k0 * KP + j],       (_Float16)wte[(k0 + 1) * KP + j]};
        wc[kk] = (f16x2){(_Float16)wte[k0 * KP + j + 160], (_Float16)wte[(k0 + 1) * KP + j + 160]};
    }

    // ---- encoder: 128 steps ----
    int idx_n = x[BATCH + b];
    float e_cur = 0.f;
    if (comb && jc < H) e_cur = enc_emb[(long)x[b] * H + jc];
    __syncthreads();

    const f16x8* hb8 = (const f16x8*)&hh[s * 80];

    for (int t = 0; t < NX; ++t) {
        int idx_n2 = x[min(t + 2, NX - 1) * BATCH + b];
        float e_nx = 0.f;
        if (comb && jc < H && t + 1 < NX) e_nx = enc_emb[(long)idx_n * H + jc];

        float p0 = 0.f, p1 = 0.f;
#pragma unroll
        for (int i = 0; i < 10; ++i) {
            f16x8 hv = hb8[i];
            f16x2 q0 = {hv[0], hv[1]}, q1 = {hv[2], hv[3]};
            f16x2 q2 = {hv[4], hv[5]}, q3 = {hv[6], hv[7]};
            p0 = __builtin_amdgcn_fdot2(wa[4 * i + 0], q0, p0, false);
            p1 = __builtin_amdgcn_fdot2(wc[4 * i + 0], q0, p1, false);
            p0 = __builtin_amdgcn_fdot2(wa[4 * i + 1], q1, p0, false);
            p1 = __builtin_amdgcn_fdot2(wc[4 * i + 1], q1, p1, false);
            p0 = __builtin_amdgcn_fdot2(wa[4 * i + 2], q2, p0, false);
            p1 = __builtin_amdgcn_fdot2(wc[4 * i + 2], q2, p1, false);
            p0 = __builtin_amdgcn_fdot2(wa[4 * i + 3], q3, p0, false);
            p1 = __builtin_amdgcn_fdot2(wc[4 * i + 3], q3, p1, false);
        }
        part[s * 320 + j] = p0;
        part[s * 320 + 160 + j] = p1;
        __syncthreads();
        if (comb) {
            float v = part[jc] + part[320 + jc] + part[640 + jc] + part[960 + jc] + be + e_cur;
            hh[jc] = (_Float16)fmaxf(v, 0.f);
        }
        __syncthreads();
        e_cur = e_nx; idx_n = idx_n2;
    }

    // ---- reload decoder weights ----
#pragma unroll
    for (int kk = 0; kk < 40; ++kk) {
        int k0 = s * 80 + 2 * kk;
        wa[kk] = (f16x2){(_Float16)wtd[k0 * KP + j],       (_Float16)wtd[(k0 + 1) * KP + j]};
        wc[kk] = (f16x2){(_Float16)wtd[k0 * KP + j + 160], (_Float16)wtd[(k0 + 1) * KP + j + 160]};
    }

    // ---- decoder: 127 steps; fp8 h rows -> A8 via coalesced u32 ----
    idx_n = y[BATCH + b];
    e_cur = 0.f;
    if (comb && jc < H) e_cur = dec_emb[(long)y[b] * H + jc];

    for (int t = 0; t < NY - 1; ++t) {
        int idx_n2 = y[min(t + 2, NY - 1) * BATCH + b];
        float e_nx = 0.f;
        if (comb && jc < H && t + 1 < NY - 1) e_nx = dec_emb[(long)idx_n * H + jc];

        float p0 = 0.f, p1 = 0.f;
#pragma unroll
        for (int i = 0; i < 10; ++i) {
            f16x8 hv = hb8[i];
            f16x2 q0 = {hv[0], hv[1]}, q1 = {hv[2], hv[3]};
            f16x2 q2 = {hv[4], hv[5]}, q3 = {hv[6], hv[7]};
            p0 = __builtin_amdgcn_fdot2(wa[4 * i + 0], q0, p0, false);
            p1 = __builtin_amdgcn_fdot2(wc[4 * i + 0], q0, p1, false);
            p0 = __builtin_amdgcn_fdot2(wa[4 * i + 1], q1, p0, false);
            p1 = __builtin_amdgcn_fdot2(wc[4 * i + 1], q1, p1, false);
            p0 = __builtin_amdgcn_fdot2(wa[4 * i + 2], q2, p0, false);
            p1 = __builtin_amdgcn_fdot2(wc[4 * i + 2], q2, p1, false);
            p0 = __builtin_amdgcn_fdot2(wa[4 * i + 3], q3, p0, false);
            p1 = __builtin_amdgcn_fdot2(wc[4 * i + 3], q3, p1, false);
        }
        part[s * 320 + j] = p0;
        part[s * 320 + 160 + j] = p1;
        __syncthreads();
        if (comb) {
            float v = part[jc] + part[320 + jc] + part[640 + jc] + part[960 + jc] + bd + e_cur;
            v = fmaxf(v, 0.f);
            hh[jc] = (_Float16)v;
            int pk = __builtin_amdgcn_cvt_pk_fp8_f32(v, v, 0, false);
            a8row[jc] = (u8)(pk & 0xff);
        }
        __syncthreads();
        if (tid < 80)   // coalesced 320B row store
            ((unsigned int*)(A8 + (long)(t * BATCH + b) * KP))[tid] =
                ((const unsigned int*)a8row)[tid];
        e_cur = e_nx; idx_n = idx_n2;
    }
}

// ---------------- K2: fp8 logits GEMM + exp row-sum ----------------------
// 508 rowblocks (64 rows) x 8 colgroups (cg==XCD slice of OWS for L2 hits).
// A tile in LDS, 336-stride (b64 frag reads hit 4 accesses/bank = conflict-
// free minimum). B fragments ping-pong through 4 rotating register buffers,
// prefetch distance 2 -- loads stay in flight across the exp epilogue, no
// barriers in the K-loop. ~140 VGPR -> 3 blocks/CU.
__global__ __launch_bounds__(256, 3) void k2_gemm(const u8* __restrict__ A8,
                                                  const u8* __restrict__ OWS,
                                                  const float* __restrict__ obp,
                                                  float* __restrict__ sumexp) {
    const int tid = threadIdx.x;
    const int lane = tid & 63, wave = tid >> 6;     // wave == col-slice
    const int lane16 = lane & 15, quad = lane >> 4;
    const int cg = blockIdx.x & 7;
    const int rb = blockIdx.x >> 3;
    const int colbase = cg * 4096;

    __shared__ u8 Ald[64 * 336];
    __shared__ float rowsum[64];
    if (tid < 64) rowsum[tid] = 0.f;

    // stage A tile: 64 rows x 320B -> LDS stride 336
    {
        const u8* ag = A8 + (long)rb * 64 * KP;
#pragma unroll
        for (int i = 0; i < 5; ++i) {
            int t2 = i * 256 + tid;
            int row = t2 / 20, o = t2 % 20;
            *(uint4*)&Ald[row * 336 + o * 16] = *(const uint4*)(ag + row * 320 + o * 16);
        }
    }
    __syncthreads();

    // wave's B base: tile = cg*64 + ct*4 + wave; slice f=ct*10+ks at
    // wb + (f/10)*81920 + (f%10)*2048 (+ tc*512 + lane*8)
    const u8* wb = OWS + (long)(cg * 64 + wave) * 20480 + lane * 8;

    long bb[4][4];                     // 4 rotating buffers x 4 tc
#pragma unroll
    for (int tc = 0; tc < 4; ++tc) {
        bb[0][tc] = *(const long*)(wb + tc * 512);
        bb[1][tc] = *(const long*)(wb + 2048 + tc * 512);
    }

    f32x4 acc[4][4];
#pragma unroll
    for (int p = 0; p < 4; ++p)
#pragma unroll
        for (int q = 0; q < 4; ++q) acc[p][q] = (f32x4){0.f, 0.f, 0.f, 0.f};

    float rsum[16];
#pragma unroll
    for (int i = 0; i < 16; ++i) rsum[i] = 0.f;

    const u8* pB = wb;                 // advances 2 col-tiles (163840 B) per cc
    for (int cc = 0; cc < 8; ++cc) {
#pragma unroll
        for (int u = 0; u < 20; ++u) {           // two col-tiles, 10 k-slices each
            const int ks = (u < 10) ? u : u - 10;
            // prefetch slice u+2 (static offset; overruns land in OWS_PAD)
            {
                const int u2 = u + 2;
                const u8* pf = pB + (u2 / 10) * 81920 + (u2 % 10) * 2048;
#pragma unroll
                for (int tc = 0; tc < 4; ++tc)
                    bb[(u + 2) & 3][tc] = *(const long*)(pf + tc * 512);
            }
            // A fragments from LDS (conflict-free b64)
            long av[4];
#pragma unroll
            for (int rt = 0; rt < 4; ++rt)
                av[rt] = *(const long*)&Ald[(rt * 16 + lane16) * 336 + ks * 32 + quad * 8];
#pragma unroll
            for (int rt = 0; rt < 4; ++rt)
#pragma unroll
                for (int tc = 0; tc < 4; ++tc)
                    acc[rt][tc] = __builtin_amdgcn_mfma_f32_16x16x32_fp8_fp8(
                        av[rt], bb[u & 3][tc], acc[rt][tc], 0, 0, 0);

            if (ks == 9) {                        // epilogue; pad cols: obp=-1e30 -> exp=0
                int ct = cc * 2 + (u >= 10);
                int cb = colbase + ct * 256 + wave * 64;
#pragma unroll
                for (int tc = 0; tc < 4; ++tc) {
                    float ob = obp[cb + tc * 16 + lane16];
#pragma unroll
                    for (int rt = 0; rt < 4; ++rt) {
#pragma unroll
                        for (int i = 0; i < 4; ++i)
                            rsum[rt * 4 + i] += __expf(acc[rt][tc][i] + ob);
                        acc[rt][tc] = (f32x4){0.f, 0.f, 0.f, 0.f};
                    }
                }
            }
        }
        pB += 163840;
    }

    // reduce over 16 column-lanes; lane16==0 holds rows quad*4+i per rt
#pragma unroll
    for (int m = 1; m < 16; m <<= 1)
#pragma unroll
        for (int i = 0; i < 16; ++i) rsum[i] += __shfl_xor(rsum[i], m, 64);
    if (lane16 == 0) {
#pragma unroll
        for (int rt = 0; rt < 4; ++rt)
#pragma unroll
            for (int i = 0; i < 4; ++i)
                atomicAdd(&rowsum[rt * 16 + quad * 4 + i], rsum[rt * 4 + i]);
    }
    __syncthreads();
    if (tid < 64) atomicAdd(&sumexp[(long)rb * 64 + tid], rowsum[tid]);
}

// ---------------- K3: target logit + CE + final reduce -------------------
// W target row from swizzled OWS: lane l<40 -> (ks=l>>2, quad=l&3) u64 at
// tile(tgt) + ks*2048 + ((tgt>>4)&3)*512 + (tgt&15)*8 + quad*128.
__global__ __launch_bounds__(256) void k3_ce(const u8* __restrict__ A8,
                                             const u8* __restrict__ OWS,
                                             const float* __restrict__ outb,
                                             const float* __restrict__ sumexp,
                                             const int* __restrict__ y,
                                             float* __restrict__ out) {
    const int wave = threadIdx.x >> 6, lane = threadIdx.x & 63;
    const int r = blockIdx.x * 4 + wave;         // 0..32511
    const int t = r >> 8, b = r & 255;
    const int tgt = y[(t + 1) * BATCH + b];
    float s = 0.f;
    if (lane < 40) {
        unsigned long long av = *(const unsigned long long*)(A8 + (long)r * KP + lane * 8);
        long wdst = (long)(tgt >> 6) * 20480 + (lane >> 2) * 2048
                  + ((tgt >> 4) & 3) * 512 + (tgt & 15) * 8 + (lane & 3) * 128;
        unsigned long long wv = *(const unsigned long long*)(OWS + wdst);
        unsigned int a4 = (unsigned int)av, a4h = (unsigned int)(av >> 32);
        unsigned int w4 = (unsigned int)wv, w4h = (unsigned int)(wv >> 32);
        f32x2 al = __builtin_amdgcn_cvt_pk_f32_fp8(a4, false);
        f32x2 ah = __builtin_amdgcn_cvt_pk_f32_fp8(a4, true);
        f32x2 wl = __builtin_amdgcn_cvt_pk_f32_fp8(w4, false);
        f32x2 wh = __builtin_amdgcn_cvt_pk_f32_fp8(w4, true);
        s += al[0] * wl[0] + al[1] * wl[1] + ah[0] * wh[0] + ah[1] * wh[1];
        al = __builtin_amdgcn_cvt_pk_f32_fp8(a4h, false);
        ah = __builtin_amdgcn_cvt_pk_f32_fp8(a4h, true);
        wl = __builtin_amdgcn_cvt_pk_f32_fp8(w4h, false);
        wh = __builtin_amdgcn_cvt_pk_f32_fp8(w4h, true);
        s += al[0] * wl[0] + al[1] * wl[1] + ah[0] * wh[0] + ah[1] * wh[1];
    }
#pragma unroll
    for (int m = 1; m < 64; m <<= 1) s += __shfl_xor(s, m, 64);
    __shared__ float part[4];
    if (lane == 0) part[wave] = logf(sumexp[r]) - (s + outb[tgt]);
    __syncthreads();
    if (threadIdx.x == 0) {
        float tot = part[0] + part[1] + part[2] + part[3];
        atomicAdd(out, tot * (1.0f / 256.0f));
    }
}

// ---------------- launch --------------------------------------------------
extern "C" void kernel_launch(void* const* d_in, const int* in_sizes, int n_in,
                              void* d_out, int out_size, void* d_ws, size_t ws_size,
                              hipStream_t stream) {
    (void)in_sizes; (void)n_in; (void)out_size; (void)ws_size;
    const int*   x       = (const int*)d_in[0];
    const int*   y       = (const int*)d_in[1];
    const float* enc_emb = (const float*)d_in[2];
    const float* encW    = (const float*)d_in[3];
    const float* encb    = (const float*)d_in[4];
    const float* dec_emb = (const float*)d_in[5];
    const float* decW    = (const float*)d_in[6];
    const float* decb    = (const float*)d_in[7];
    const float* outW    = (const float*)d_in[8];
    const float* outb    = (const float*)d_in[9];

    char* ws = (char*)d_ws;
    u8* ows  = (u8*)(ws + OWS_OFF);
    u8* A8   = (u8*)(ws + A8_OFF);
    float* wte    = (float*)(ws + WTE_OFF);
    float* wtd    = (float*)(ws + WTD_OFF);
    float* obp    = (float*)(ws + OBP_OFF);
    float* sumexp = (float*)(ws + SE_OFF);

    hipMemsetAsync(sumexp, 0, SE_BYTES, stream);
    hipMemsetAsync(d_out, 0, sizeof(float), stream);

    long n0 = (long)NPAD * KP / 4 + NPAD + 2L * 320 * KP;
    k0_prep<<<(int)((n0 + 255) / 256), 256, 0, stream>>>(outW, encW, decW, outb,
                                                         ows, obp, wte, wtd);
    k1_rnn<<<256, 640, 0, stream>>>(x, y, enc_emb, dec_emb, encb, decb, wte, wtd, A8);
    k2_gemm<<<508 * 8, 256, 0, stream>>>(A8, ows, obp, sumexp);
    k3_ce<<<8128, 256, 0, stream>>>(A8, ows, outb, sumexp, y, (float*)d_out);
}

// Round 8
// 1006.919 us; speedup vs baseline: 2.2289x; 2.2289x over previous
//
#include <hip/hip_runtime.h>
#include <hip/hip_bf16.h>
#include <stdint.h>

typedef unsigned short u16;
typedef unsigned char u8;
typedef float f32x4 __attribute__((ext_vector_type(4)));
typedef float f32x2 __attribute__((ext_vector_type(2)));
typedef _Float16 f16x2 __attribute__((ext_vector_type(2)));
typedef _Float16 f16x8 __attribute__((ext_vector_type(8)));

#define H      300
#define KP     320          // K padded (320 fp8 bytes per row)
#define BATCH  256
#define NX     128
#define NY     128
#define VY     32000
#define NPAD   32768        // vocab padded
#define MROWS  32512        // 127*256 decoder rows

// Swizzled OW layout (OWS): vocab col v, k -> tile = v>>6 (64 cols x 320 K =
// 20480 B each); within tile: byte = (k>>5)*2048 + ((v>>4)&3)*512 + (v&15)*8
// + ((k>>3)&3)*128 + (k&7).  A wave's MFMA B-fragment (16-col block tc,
// k-slice ks) is the contiguous 512B range [tile*20480 + ks*2048 + tc*512
// + lane*8] -- fully coalesced b64 loads straight to VGPRs.

// workspace layout (bytes)
#define OWS_OFF   0UL
#define OWS_BYTES ((unsigned long)NPAD * KP)           // 10,485,760
#define OWS_PAD   131072UL
#define A8_OFF    (OWS_OFF + OWS_BYTES + OWS_PAD)
#define A8_BYTES  ((unsigned long)MROWS * KP)          // 10,403,840
#define WTE_OFF   (A8_OFF + A8_BYTES)
#define WT_BYTES  (320UL * KP * 4)                     // 320 rows (zero-pad k>=300)
#define WTD_OFF   (WTE_OFF + WT_BYTES)
#define OBP_OFF   (WTD_OFF + WT_BYTES)
#define OBP_BYTES ((unsigned long)NPAD * 4)            // outb with -1e30 pad
#define SE_OFF    (OBP_OFF + OBP_BYTES)
#define SE_BYTES  ((unsigned long)MROWS * 4)

// ---------------- K0: prep (fp8 outW -> swizzled OWS; padded outb; W^T) ----
__global__ __launch_bounds__(256) void k0_prep(const float* __restrict__ outW,
                                               const float* __restrict__ encW,
                                               const float* __restrict__ decW,
                                               const float* __restrict__ outb,
                                               u8* __restrict__ ows,
                                               float* __restrict__ obp,
                                               float* __restrict__ wte,
                                               float* __restrict__ wtd) {
    long id = (long)blockIdx.x * 256 + threadIdx.x;
    const long n1 = (long)NPAD * KP / 4;         // u32 chunks
    if (id < n1) {
        int v = (int)(id / 80), k4 = (int)(id % 80) * 4;
        float4 f = {0.f, 0.f, 0.f, 0.f};
        if (v < VY && k4 < H) f = *(const float4*)&outW[(long)v * H + k4]; // k4<=296 -> full
        int w = __builtin_amdgcn_cvt_pk_fp8_f32(f.x, f.y, 0, false);
        w = __builtin_amdgcn_cvt_pk_fp8_f32(f.z, f.w, w, true);
        long dst = (long)(v >> 6) * 20480 + (k4 >> 5) * 2048 + ((v >> 4) & 3) * 512
                 + (v & 15) * 8 + ((k4 >> 3) & 3) * 128 + (k4 & 7);
        *(unsigned int*)(ows + dst) = (unsigned int)w;
        return;
    }
    long id2 = id - n1;
    if (id2 < NPAD) {                            // padded bias: pad -> -1e30
        obp[id2] = (id2 < VY) ? outb[id2] : -1e30f;
        return;
    }
    id2 -= NPAD;
    if (id2 < 320L * KP) {                       // Wt_enc[k][j] = encW[j][k], 320 rows
        int k = (int)(id2 / KP), j = (int)(id2 % KP);
        wte[id2] = (k < H && j < H) ? encW[j * H + k] : 0.f;
        return;
    }
    id2 -= 320L * KP;
    if (id2 < 320L * KP) {                       // Wt_dec
        int k = (int)(id2 / KP), j = (int)(id2 % KP);
        wtd[id2] = (k < H && j < H) ? decW[j * H + k] : 0.f;
    }
}

// ---------------- K1: register-resident weights, 1 batch elem / block ----
// 256 blocks x 640 threads (10 waves). Thread (s=tid/160, j=tid%160) holds
// W[:, {j, j+160}] for k in [80s, 80s+80) as 80 packed f16 pairs; each b128
// h-broadcast read feeds 8 fdot2 (2 cols x 4 pairs).
__global__ __launch_bounds__(640) void k1_rnn(const int* __restrict__ x,
                                              const int* __restrict__ y,
                                              const float* __restrict__ enc_emb,
                                              const float* __restrict__ dec_emb,
                                              const float* __restrict__ encb,
                                              const float* __restrict__ decb,
                                              const float* __restrict__ wte,
                                              const float* __restrict__ wtd,
                                              u8* __restrict__ A8) {
    const int tid = threadIdx.x;
    const int s = tid / 160;           // k-slice 0..3
    const int j = tid - s * 160;       // column pair base: cols j, j+160
    const int b = blockIdx.x;

    __shared__ __align__(16) _Float16 hh[320];   // h (fp16), pad >=300 = 0
    __shared__ float part[1280];                 // [slice][col]
    __shared__ __align__(4) u8 a8row[320];

    for (int i = tid; i < 320; i += 640) hh[i] = (_Float16)0.f;

    const bool comb = (tid < 320);     // combine-phase threads, col jc
    const int jc = tid;
    const float be = (comb && jc < H) ? encb[jc] : 0.f;
    const float bd = (comb && jc < H) ? decb[jc] : 0.f;

    // ---- preload encoder weights (2 cols x 40 pairs) ----
    f16x2 wa[40], wc[40];
#pragma unroll
    for (int kk = 0; kk < 40; ++kk) {
        int k0 = s * 80 + 2 * kk;
        wa[kk] = (f16x2){(_Float16)wte[k0 * KP + j],       (_Float16)wte[(k0 + 1) * KP + j]};
        wc[kk] = (f16x2){(_Float16)wte[k0 * KP + j + 160], (_Float16)wte[(k0 + 1) * KP + j + 160]};
    }

    // ---- encoder: 128 steps ----
    int idx_n = x[BATCH + b];
    float e_cur = 0.f;
    if (comb && jc < H) e_cur = enc_emb[(long)x[b] * H + jc];
    __syncthreads();

    const f16x8* hb8 = (const f16x8*)&hh[s * 80];

    for (int t = 0; t < NX; ++t) {
        int idx_n2 = x[min(t + 2, NX - 1) * BATCH + b];
        float e_nx = 0.f;
        if (comb && jc < H && t + 1 < NX) e_nx = enc_emb[(long)idx_n * H + jc];

        float p0 = 0.f, p1 = 0.f;
#pragma unroll
        for (int i = 0; i < 10; ++i) {
            f16x8 hv = hb8[i];
            f16x2 q0 = {hv[0], hv[1]}, q1 = {hv[2], hv[3]};
            f16x2 q2 = {hv[4], hv[5]}, q3 = {hv[6], hv[7]};
            p0 = __builtin_amdgcn_fdot2(wa[4 * i + 0], q0, p0, false);
            p1 = __builtin_amdgcn_fdot2(wc[4 * i + 0], q0, p1, false);
            p0 = __builtin_amdgcn_fdot2(wa[4 * i + 1], q1, p0, false);
            p1 = __builtin_amdgcn_fdot2(wc[4 * i + 1], q1, p1, false);
            p0 = __builtin_amdgcn_fdot2(wa[4 * i + 2], q2, p0, false);
            p1 = __builtin_amdgcn_fdot2(wc[4 * i + 2], q2, p1, false);
            p0 = __builtin_amdgcn_fdot2(wa[4 * i + 3], q3, p0, false);
            p1 = __builtin_amdgcn_fdot2(wc[4 * i + 3], q3, p1, false);
        }
        part[s * 320 + j] = p0;
        part[s * 320 + 160 + j] = p1;
        __syncthreads();
        if (comb) {
            float v = part[jc] + part[320 + jc] + part[640 + jc] + part[960 + jc] + be + e_cur;
            hh[jc] = (_Float16)fmaxf(v, 0.f);
        }
        __syncthreads();
        e_cur = e_nx; idx_n = idx_n2;
    }

    // ---- reload decoder weights ----
#pragma unroll
    for (int kk = 0; kk < 40; ++kk) {
        int k0 = s * 80 + 2 * kk;
        wa[kk] = (f16x2){(_Float16)wtd[k0 * KP + j],       (_Float16)wtd[(k0 + 1) * KP + j]};
        wc[kk] = (f16x2){(_Float16)wtd[k0 * KP + j + 160], (_Float16)wtd[(k0 + 1) * KP + j + 160]};
    }

    // ---- decoder: 127 steps; fp8 h rows -> A8 via coalesced u32 ----
    idx_n = y[BATCH + b];
    e_cur = 0.f;
    if (comb && jc < H) e_cur = dec_emb[(long)y[b] * H + jc];

    for (int t = 0; t < NY - 1; ++t) {
        int idx_n2 = y[min(t + 2, NY - 1) * BATCH + b];
        float e_nx = 0.f;
        if (comb && jc < H && t + 1 < NY - 1) e_nx = dec_emb[(long)idx_n * H + jc];

        float p0 = 0.f, p1 = 0.f;
#pragma unroll
        for (int i = 0; i < 10; ++i) {
            f16x8 hv = hb8[i];
            f16x2 q0 = {hv[0], hv[1]}, q1 = {hv[2], hv[3]};
            f16x2 q2 = {hv[4], hv[5]}, q3 = {hv[6], hv[7]};
            p0 = __builtin_amdgcn_fdot2(wa[4 * i + 0], q0, p0, false);
            p1 = __builtin_amdgcn_fdot2(wc[4 * i + 0], q0, p1, false);
            p0 = __builtin_amdgcn_fdot2(wa[4 * i + 1], q1, p0, false);
            p1 = __builtin_amdgcn_fdot2(wc[4 * i + 1], q1, p1, false);
            p0 = __builtin_amdgcn_fdot2(wa[4 * i + 2], q2, p0, false);
            p1 = __builtin_amdgcn_fdot2(wc[4 * i + 2], q2, p1, false);
            p0 = __builtin_amdgcn_fdot2(wa[4 * i + 3], q3, p0, false);
            p1 = __builtin_amdgcn_fdot2(wc[4 * i + 3], q3, p1, false);
        }
        part[s * 320 + j] = p0;
        part[s * 320 + 160 + j] = p1;
        __syncthreads();
        if (comb) {
            float v = part[jc] + part[320 + jc] + part[640 + jc] + part[960 + jc] + bd + e_cur;
            v = fmaxf(v, 0.f);
            hh[jc] = (_Float16)v;
            int pk = __builtin_amdgcn_cvt_pk_fp8_f32(v, v, 0, false);
            a8row[jc] = (u8)(pk & 0xff);
        }
        __syncthreads();
        if (tid < 80)   // coalesced 320B row store
            ((unsigned int*)(A8 + (long)(t * BATCH + b) * KP))[tid] =
                ((const unsigned int*)a8row)[tid];
        e_cur = e_nx; idx_n = idx_n2;
    }
}

// ---------------- K2: fp8 logits GEMM + exp row-sum, zero-LDS ------------
// R6 structure (known-good): A in 80 VGPRs, B coalesced b64 loads from
// swizzled OWS, dynamic ct loop, fully-unrolled ks. One contained addition:
// nb0/nb1 (+16 VGPR) hold next-ct slices 0-1, issued after the last MFMA of
// ct but BEFORE the exp epilogue, hiding the ct-boundary L2 latency.
__global__ __launch_bounds__(256, 2) void k2_gemm(const u8* __restrict__ A8,
                                                  const u8* __restrict__ OWS,
                                                  const float* __restrict__ obp,
                                                  float* __restrict__ sumexp) {
    const int tid = threadIdx.x;
    const int lane = tid & 63, wave = tid >> 6;     // wave == col-slice
    const int lane16 = lane & 15, quad = lane >> 4;
    const int cg = blockIdx.x & 7;
    const int rb = blockIdx.x >> 3;
    const int colbase = cg * 4096;

    __shared__ float rowsum[64];
    if (tid < 64) rowsum[tid] = 0.f;
    __syncthreads();

    // ---- A fragments -> registers (64 rows x K=320; same for all 4 waves)
    long a[4][10];
    {
        const u8* abase = A8 + ((long)rb * 64 + lane16) * KP + quad * 8;
#pragma unroll
        for (int rt = 0; rt < 4; ++rt)
#pragma unroll
            for (int ks = 0; ks < 10; ++ks)
                a[rt][ks] = *(const long*)(abase + rt * 16 * KP + ks * 32);
    }

    // wave's B base: tile = cg*64 + ct*4 + wave
    const u8* wb = OWS + (long)(cg * 64 + wave) * 20480 + lane * 8;

    float rsum[16];
#pragma unroll
    for (int i = 0; i < 16; ++i) rsum[i] = 0.f;

    // preload ct=0 slices 0,1
    long nb0[4], nb1[4];
#pragma unroll
    for (int tc = 0; tc < 4; ++tc) {
        nb0[tc] = *(const long*)(wb + tc * 512);
        nb1[tc] = *(const long*)(wb + 2048 + tc * 512);
    }

    for (int ct = 0; ct < 16; ++ct) {
        const u8* ctp = wb + (long)ct * 81920;       // 4 tiles * 20480
        f32x4 acc[4][4];
#pragma unroll
        for (int p = 0; p < 4; ++p)
#pragma unroll
            for (int q = 0; q < 4; ++q) acc[p][q] = (f32x4){0.f, 0.f, 0.f, 0.f};

        // ks = 0,1 from the preloaded registers
#pragma unroll
        for (int rt = 0; rt < 4; ++rt)
#pragma unroll
            for (int tc = 0; tc < 4; ++tc)
                acc[rt][tc] = __builtin_amdgcn_mfma_f32_16x16x32_fp8_fp8(
                    a[rt][0], nb0[tc], acc[rt][tc], 0, 0, 0);
#pragma unroll
        for (int rt = 0; rt < 4; ++rt)
#pragma unroll
            for (int tc = 0; tc < 4; ++tc)
                acc[rt][tc] = __builtin_amdgcn_mfma_f32_16x16x32_fp8_fp8(
                    a[rt][1], nb1[tc], acc[rt][tc], 0, 0, 0);

        // ks = 2..9 straight from OWS (compiler-scheduled, as in R6)
#pragma unroll
        for (int ks = 2; ks < 10; ++ks) {
            const u8* p = ctp + ks * 2048;
            long bfr[4];
#pragma unroll
            for (int tc = 0; tc < 4; ++tc)
                bfr[tc] = *(const long*)(p + tc * 512);
#pragma unroll
            for (int rt = 0; rt < 4; ++rt)
#pragma unroll
                for (int tc = 0; tc < 4; ++tc)
                    acc[rt][tc] = __builtin_amdgcn_mfma_f32_16x16x32_fp8_fp8(
                        a[rt][ks], bfr[tc], acc[rt][tc], 0, 0, 0);
        }

        // issue next-ct slice 0,1 loads BEFORE the epilogue (clamped at tail)
        {
            const u8* np = wb + (long)min(ct + 1, 15) * 81920;
#pragma unroll
            for (int tc = 0; tc < 4; ++tc) {
                nb0[tc] = *(const long*)(np + tc * 512);
                nb1[tc] = *(const long*)(np + 2048 + tc * 512);
            }
        }

        // epilogue (branch-free: obp pad = -1e30 -> exp = 0)
        int cb = colbase + ct * 256 + wave * 64;
#pragma unroll
        for (int tc = 0; tc < 4; ++tc) {
            float ob = obp[cb + tc * 16 + lane16];
#pragma unroll
            for (int rt = 0; rt < 4; ++rt)
#pragma unroll
                for (int i = 0; i < 4; ++i)
                    rsum[rt * 4 + i] += __expf(acc[rt][tc][i] + ob);
        }
    }

    // reduce over 16 column-lanes; lane16==0 holds rows quad*4+i per rt
#pragma unroll
    for (int m = 1; m < 16; m <<= 1)
#pragma unroll
        for (int i = 0; i < 16; ++i) rsum[i] += __shfl_xor(rsum[i], m, 64);
    if (lane16 == 0) {
#pragma unroll
        for (int rt = 0; rt < 4; ++rt)
#pragma unroll
            for (int i = 0; i < 4; ++i)
                atomicAdd(&rowsum[rt * 16 + quad * 4 + i], rsum[rt * 4 + i]);
    }
    __syncthreads();
    if (tid < 64) atomicAdd(&sumexp[(long)rb * 64 + tid], rowsum[tid]);
}

// ---------------- K3: target logit + CE + final reduce -------------------
// W target row from swizzled OWS: lane l<40 -> (ks=l>>2, quad=l&3) u64 at
// tile(tgt) + ks*2048 + ((tgt>>4)&3)*512 + (tgt&15)*8 + quad*128.
__global__ __launch_bounds__(256) void k3_ce(const u8* __restrict__ A8,
                                             const u8* __restrict__ OWS,
                                             const float* __restrict__ outb,
                                             const float* __restrict__ sumexp,
                                             const int* __restrict__ y,
                                             float* __restrict__ out) {
    const int wave = threadIdx.x >> 6, lane = threadIdx.x & 63;
    const int r = blockIdx.x * 4 + wave;         // 0..32511
    const int t = r >> 8, b = r & 255;
    const int tgt = y[(t + 1) * BATCH + b];
    float s = 0.f;
    if (lane < 40) {
        unsigned long long av = *(const unsigned long long*)(A8 + (long)r * KP + lane * 8);
        long wdst = (long)(tgt >> 6) * 20480 + (lane >> 2) * 2048
                  + ((tgt >> 4) & 3) * 512 + (tgt & 15) * 8 + (lane & 3) * 128;
        unsigned long long wv = *(const unsigned long long*)(OWS + wdst);
        unsigned int a4 = (unsigned int)av, a4h = (unsigned int)(av >> 32);
        unsigned int w4 = (unsigned int)wv, w4h = (unsigned int)(wv >> 32);
        f32x2 al = __builtin_amdgcn_cvt_pk_f32_fp8(a4, false);
        f32x2 ah = __builtin_amdgcn_cvt_pk_f32_fp8(a4, true);
        f32x2 wl = __builtin_amdgcn_cvt_pk_f32_fp8(w4, false);
        f32x2 wh = __builtin_amdgcn_cvt_pk_f32_fp8(w4, true);
        s += al[0] * wl[0] + al[1] * wl[1] + ah[0] * wh[0] + ah[1] * wh[1];
        al = __builtin_amdgcn_cvt_pk_f32_fp8(a4h, false);
        ah = __builtin_amdgcn_cvt_pk_f32_fp8(a4h, true);
        wl = __builtin_amdgcn_cvt_pk_f32_fp8(w4h, false);
        wh = __builtin_amdgcn_cvt_pk_f32_fp8(w4h, true);
        s += al[0] * wl[0] + al[1] * wl[1] + ah[0] * wh[0] + ah[1] * wh[1];
    }
#pragma unroll
    for (int m = 1; m < 64; m <<= 1) s += __shfl_xor(s, m, 64);
    __shared__ float part[4];
    if (lane == 0) part[wave] = logf(sumexp[r]) - (s + outb[tgt]);
    __syncthreads();
    if (threadIdx.x == 0) {
        float tot = part[0] + part[1] + part[2] + part[3];
        atomicAdd(out, tot * (1.0f / 256.0f));
    }
}

// ---------------- launch --------------------------------------------------
extern "C" void kernel_launch(void* const* d_in, const int* in_sizes, int n_in,
                              void* d_out, int out_size, void* d_ws, size_t ws_size,
                              hipStream_t stream) {
    (void)in_sizes; (void)n_in; (void)out_size; (void)ws_size;
    const int*   x       = (const int*)d_in[0];
    const int*   y       = (const int*)d_in[1];
    const float* enc_emb = (const float*)d_in[2];
    const float* encW    = (const float*)d_in[3];
    const float* encb    = (const float*)d_in[4];
    const float* dec_emb = (const float*)d_in[5];
    const float* decW    = (const float*)d_in[6];
    const float* decb    = (const float*)d_in[7];
    const float* outW    = (const float*)d_in[8];
    const float* outb    = (const float*)d_in[9];

    char* ws = (char*)d_ws;
    u8* ows  = (u8*)(ws + OWS_OFF);
    u8* A8   = (u8*)(ws + A8_OFF);
    float* wte    = (float*)(ws + WTE_OFF);
    float* wtd    = (float*)(ws + WTD_OFF);
    float* obp    = (float*)(ws + OBP_OFF);
    float* sumexp = (float*)(ws + SE_OFF);

    hipMemsetAsync(sumexp, 0, SE_BYTES, stream);
    hipMemsetAsync(d_out, 0, sizeof(float), stream);

    long n0 = (long)NPAD * KP / 4 + NPAD + 2L * 320 * KP;
    k0_prep<<<(int)((n0 + 255) / 256), 256, 0, stream>>>(outW, encW, decW, outb,
                                                         ows, obp, wte, wtd);
    k1_rnn<<<256, 640, 0, stream>>>(x, y, enc_emb, dec_emb, encb, decb, wte, wtd, A8);
    k2_gemm<<<508 * 8, 256, 0, stream>>>(A8, ows, obp, sumexp);
    k3_ce<<<8128, 256, 0, stream>>>(A8, ows, outb, sumexp, y, (float*)d_out);
}